// Round 6
// baseline (425.527 us; speedup 1.0000x reference)
//
#include <hip/hip_runtime.h>

// B=256, T=256, DM=384, DK=DV=64.
// Round 6: DIAGNOSTIC. Real kernels = round-0 champion (unchanged, correct
// output). Three probe kernels (write only to workspace) repeat phase groups
// so per-phase marginal cost appears in the rocprof dispatch table:
//   probe_p12 : phases 1+2, GEMM mega-loop x3          -> P1 = (d-const)/3
//   probe_p3  : phases 1+2 once, {S=QK^T + softmax} x5 -> P3 = (d-P12)/5
//   probe_p234: phases 1+2 once, {S + softmax + PV} x3 -> P4 by subtraction
// Probes keep grid 256 x 1024thr and the full 144KiB LDS map so they run in
// the same 1-block/CU latency regime as the champion.

typedef __attribute__((ext_vector_type(8))) short short8;
typedef __attribute__((ext_vector_type(4))) float floatx4;

__device__ inline unsigned short f2bf(float f) {
  union { float f; unsigned u; } v; v.f = f;
  unsigned r = v.u + 0x7FFFu + ((v.u >> 16) & 1u);  // RNE
  return (unsigned short)(r >> 16);
}

__device__ inline void glds16(const void* g, void* l) {
  __builtin_amdgcn_global_load_lds(
      (const __attribute__((address_space(1))) void*)g,
      (__attribute__((address_space(3))) void*)l, 16, 0, 0);
}

// ---------------- kernel 0: weight transpose/convert (output-indexed) -------
__global__ void wt_kernel(const float* __restrict__ wq, const float* __restrict__ wk,
                          const float* __restrict__ wv, unsigned short* __restrict__ wt) {
  int idx = blockIdx.x * 256 + threadIdx.x;      // enumerates OUTPUT [mat][n][k]
  if (idx >= 3 * 64 * 384) return;
  int mat = idx / (64 * 384);
  int rem = idx % (64 * 384);
  int n = rem / 384, k = rem % 384;
  const float* w = (mat == 0) ? wq : ((mat == 1) ? wk : wv);
  wt[idx] = f2bf(w[k * 64 + n]);
}

// ---------------- kernel 1: fused QKV + attention (round-0 champion) --------
__global__ __launch_bounds__(1024) void fused_kernel(
    const float* __restrict__ x, const unsigned short* __restrict__ wt,
    float* __restrict__ out) {
  __shared__ __align__(16) unsigned short wb[2][3 * 192 * 32];  // 73728 B
  __shared__ __align__(16) unsigned short sK[256 * 72];         // 36864 B
  __shared__ __align__(16) unsigned short sVT[64 * 264];        // 33792 B

  int tid = threadIdx.x, lane = tid & 63, w = tid >> 6;
  int m = lane & 15, q = lane >> 4;
  int b = blockIdx.x;
  const float* xb = x + (size_t)b * 256 * 384;

  auto stage = [&](int mega, int buf) {
#pragma unroll
    for (int t = 0; t < 3; ++t) {
      int i = w + 16 * t;
      if (i < 36) {
        int kc = i / 12, sub = i % 12;
        int c = sub * 16 + (lane >> 2), g = lane & 3;
        glds16(wt + (size_t)c * 384 + (mega * 3 + kc) * 32 + g * 8,
               (void*)&wb[buf][kc * 6144 + sub * 512]);
      }
    }
  };

  floatx4 z = {0.f, 0.f, 0.f, 0.f};
  floatx4 acc[12];
#pragma unroll
  for (int nt = 0; nt < 12; ++nt) acc[nt] = z;

  stage(0, 0);
#pragma unroll
  for (int mega = 0; mega < 4; ++mega) {
    int buf = mega & 1;
    __syncthreads();
    if (mega < 3) stage(mega + 1, buf ^ 1);

#pragma unroll
    for (int kc = 0; kc < 3; ++kc) {
      int ks = mega * 3 + kc;
      const float* ap = xb + (size_t)(w * 16 + m) * 384 + ks * 32 + q * 8;
      float4 f0 = *(const float4*)ap;
      float4 f1 = *(const float4*)(ap + 4);
      short8 af;
      af[0] = (short)f2bf(f0.x); af[1] = (short)f2bf(f0.y);
      af[2] = (short)f2bf(f0.z); af[3] = (short)f2bf(f0.w);
      af[4] = (short)f2bf(f1.x); af[5] = (short)f2bf(f1.y);
      af[6] = (short)f2bf(f1.z); af[7] = (short)f2bf(f1.w);

      const unsigned short* wbk = &wb[buf][kc * 6144];
#pragma unroll
      for (int nt = 0; nt < 12; ++nt) {
        short8 bf = *(const short8*)&wbk[(nt * 16 + m) * 32 + q * 8];
        acc[nt] = __builtin_amdgcn_mfma_f32_16x16x32_bf16(af, bf, acc[nt], 0, 0, 0);
      }
    }
  }

  unsigned short* scr = &wb[0][0] + w * 1152;
#pragma unroll
  for (int nt = 0; nt < 8; ++nt) {
#pragma unroll
    for (int j = 0; j < 4; ++j) {
      unsigned short val = f2bf(acc[nt][j]);
      int lrow = q * 4 + j;
      if (nt < 4) scr[lrow * 72 + nt * 16 + m] = val;
      else        sK[(w * 16 + lrow) * 72 + (nt - 4) * 16 + m] = val;
    }
  }
#pragma unroll
  for (int nt = 8; nt < 12; ++nt) {
    ushort4 pv;
    pv.x = f2bf(acc[nt][0]); pv.y = f2bf(acc[nt][1]);
    pv.z = f2bf(acc[nt][2]); pv.w = f2bf(acc[nt][3]);
    *(ushort4*)&sVT[((nt - 8) * 16 + m) * 264 + w * 16 + q * 4] = pv;
  }

  short8 qf0 = *(const short8*)(scr + m * 72 + q * 8);
  short8 qf1 = *(const short8*)(scr + m * 72 + 32 + q * 8);

  __syncthreads();

  floatx4 sacc[16];
#pragma unroll
  for (int nt = 0; nt < 16; ++nt) {
    if (nt > w) continue;
    short8 kb0 = *(const short8*)(sK + (nt * 16 + m) * 72 + q * 8);
    short8 kb1 = *(const short8*)(sK + (nt * 16 + m) * 72 + 32 + q * 8);
    floatx4 t = __builtin_amdgcn_mfma_f32_16x16x32_bf16(qf0, kb0, z, 0, 0, 0);
    sacc[nt] = __builtin_amdgcn_mfma_f32_16x16x32_bf16(qf1, kb1, t, 0, 0, 0);
  }

  const float CSC = 0.18033688011112042f;
  float inv_[4];
  int rbase = w * 16 + q * 4;
#pragma unroll
  for (int j = 0; j < 4; ++j) {
    int rg = rbase + j;
    float sum = 0.f;
#pragma unroll
    for (int nt = 0; nt < 16; ++nt) {
      if (nt > w) continue;
      int col = nt * 16 + m;
      float p = (col <= rg) ? exp2f(sacc[nt][j] * CSC) : 0.f;
      sacc[nt][j] = p;
      sum += p;
    }
    sum += __shfl_xor(sum, 1);
    sum += __shfl_xor(sum, 2);
    sum += __shfl_xor(sum, 4);
    sum += __shfl_xor(sum, 8);
    inv_[j] = 1.f / sum;
  }

  floatx4 o[4];
#pragma unroll
  for (int vt = 0; vt < 4; ++vt) o[vt] = z;
#pragma unroll
  for (int c = 0; c < 4; ++c) {
    if (4 * c > w) continue;
#pragma unroll
    for (int t = 0; t < 4; ++t) {
      int nt = 4 * c + t;
#pragma unroll
      for (int j = 0; j < 4; ++j) {
        unsigned short pv = (nt <= w) ? f2bf(sacc[nt][j] * inv_[j]) : (unsigned short)0;
        scr[(q * 4 + j) * 72 + t * 16 + m] = pv;
      }
    }
    short8 pf0 = *(const short8*)(scr + m * 72 + q * 8);
    short8 pf1 = *(const short8*)(scr + m * 72 + 32 + q * 8);
#pragma unroll
    for (int vt = 0; vt < 4; ++vt) {
      short8 vb0 = *(const short8*)(sVT + (vt * 16 + m) * 264 + c * 64 + q * 8);
      short8 vb1 = *(const short8*)(sVT + (vt * 16 + m) * 264 + c * 64 + 32 + q * 8);
      o[vt] = __builtin_amdgcn_mfma_f32_16x16x32_bf16(pf0, vb0, o[vt], 0, 0, 0);
      o[vt] = __builtin_amdgcn_mfma_f32_16x16x32_bf16(pf1, vb1, o[vt], 0, 0, 0);
    }
  }

  float* op = out + ((size_t)b * 256 + w * 16) * 64;
#pragma unroll
  for (int vt = 0; vt < 4; ++vt)
#pragma unroll
    for (int j = 0; j < 4; ++j)
      op[(q * 4 + j) * 64 + vt * 16 + m] = o[vt][j];
}

// ================== PROBES (write to workspace only) ==================

// ---- probe 1: phases 1+2, GEMM loop x3 ----
__global__ __launch_bounds__(1024) void probe_p12(
    const float* __restrict__ x, const unsigned short* __restrict__ wt,
    float* __restrict__ dbg) {
  __shared__ __align__(16) unsigned short wb[2][3 * 192 * 32];
  __shared__ __align__(16) unsigned short sK[256 * 72];
  __shared__ __align__(16) unsigned short sVT[64 * 264];

  int tid = threadIdx.x, lane = tid & 63, w = tid >> 6;
  int m = lane & 15, q = lane >> 4;
  int b = blockIdx.x;
  const float* xb = x + (size_t)b * 256 * 384;

  auto stage = [&](int mega, int buf) {
#pragma unroll
    for (int t = 0; t < 3; ++t) {
      int i = w + 16 * t;
      if (i < 36) {
        int kc = i / 12, sub = i % 12;
        int c = sub * 16 + (lane >> 2), g = lane & 3;
        glds16(wt + (size_t)c * 384 + (mega * 3 + kc) * 32 + g * 8,
               (void*)&wb[buf][kc * 6144 + sub * 512]);
      }
    }
  };

  floatx4 z = {0.f, 0.f, 0.f, 0.f};
  floatx4 acc[12];
#pragma unroll
  for (int nt = 0; nt < 12; ++nt) acc[nt] = z;

#pragma unroll 1
  for (int rep = 0; rep < 3; ++rep) {
    asm volatile("" ::: "memory");              // defeat CSE/hoist across reps
    stage(0, 0);
#pragma unroll
    for (int mega = 0; mega < 4; ++mega) {
      int buf = mega & 1;
      __syncthreads();
      if (mega < 3) stage(mega + 1, buf ^ 1);
#pragma unroll
      for (int kc = 0; kc < 3; ++kc) {
        int ks = mega * 3 + kc;
        const float* ap = xb + (size_t)(w * 16 + m) * 384 + ks * 32 + q * 8;
        float4 f0 = *(const float4*)ap;
        float4 f1 = *(const float4*)(ap + 4);
        short8 af;
        af[0] = (short)f2bf(f0.x); af[1] = (short)f2bf(f0.y);
        af[2] = (short)f2bf(f0.z); af[3] = (short)f2bf(f0.w);
        af[4] = (short)f2bf(f1.x); af[5] = (short)f2bf(f1.y);
        af[6] = (short)f2bf(f1.z); af[7] = (short)f2bf(f1.w);
        const unsigned short* wbk = &wb[buf][kc * 6144];
#pragma unroll
        for (int nt = 0; nt < 12; ++nt) {
          short8 bf = *(const short8*)&wbk[(nt * 16 + m) * 32 + q * 8];
          acc[nt] = __builtin_amdgcn_mfma_f32_16x16x32_bf16(af, bf, acc[nt], 0, 0, 0);
        }
      }
    }
  }

  // phase 2 (once)
  unsigned short* scr = &wb[0][0] + w * 1152;
#pragma unroll
  for (int nt = 0; nt < 8; ++nt)
#pragma unroll
    for (int j = 0; j < 4; ++j) {
      unsigned short val = f2bf(acc[nt][j]);
      int lrow = q * 4 + j;
      if (nt < 4) scr[lrow * 72 + nt * 16 + m] = val;
      else        sK[(w * 16 + lrow) * 72 + (nt - 4) * 16 + m] = val;
    }
#pragma unroll
  for (int nt = 8; nt < 12; ++nt) {
    ushort4 pv;
    pv.x = f2bf(acc[nt][0]); pv.y = f2bf(acc[nt][1]);
    pv.z = f2bf(acc[nt][2]); pv.w = f2bf(acc[nt][3]);
    *(ushort4*)&sVT[((nt - 8) * 16 + m) * 264 + w * 16 + q * 4] = pv;
  }
  __syncthreads();
  float s = (float)sK[tid] + (float)sVT[tid] + (float)scr[lane];
#pragma unroll
  for (int nt = 0; nt < 12; ++nt)
#pragma unroll
    for (int j = 0; j < 4; ++j) s += acc[nt][j];
  dbg[(size_t)b * 1024 + tid] = s;
}

// ---- shared body for probes 2/3: phases 1+2 once, then rep attention ----
template <int REPS, int DO_PV>
__device__ void probe_attn_body(const float* __restrict__ x,
                                const unsigned short* __restrict__ wt,
                                float* __restrict__ dbg) {
  __shared__ __align__(16) unsigned short wb[2][3 * 192 * 32];
  __shared__ __align__(16) unsigned short sK[256 * 72];
  __shared__ __align__(16) unsigned short sVT[64 * 264];

  int tid = threadIdx.x, lane = tid & 63, w = tid >> 6;
  int m = lane & 15, q = lane >> 4;
  int b = blockIdx.x;
  const float* xb = x + (size_t)b * 256 * 384;

  auto stage = [&](int mega, int buf) {
#pragma unroll
    for (int t = 0; t < 3; ++t) {
      int i = w + 16 * t;
      if (i < 36) {
        int kc = i / 12, sub = i % 12;
        int c = sub * 16 + (lane >> 2), g = lane & 3;
        glds16(wt + (size_t)c * 384 + (mega * 3 + kc) * 32 + g * 8,
               (void*)&wb[buf][kc * 6144 + sub * 512]);
      }
    }
  };

  floatx4 z = {0.f, 0.f, 0.f, 0.f};
  floatx4 acc[12];
#pragma unroll
  for (int nt = 0; nt < 12; ++nt) acc[nt] = z;

  stage(0, 0);
#pragma unroll
  for (int mega = 0; mega < 4; ++mega) {
    int buf = mega & 1;
    __syncthreads();
    if (mega < 3) stage(mega + 1, buf ^ 1);
#pragma unroll
    for (int kc = 0; kc < 3; ++kc) {
      int ks = mega * 3 + kc;
      const float* ap = xb + (size_t)(w * 16 + m) * 384 + ks * 32 + q * 8;
      float4 f0 = *(const float4*)ap;
      float4 f1 = *(const float4*)(ap + 4);
      short8 af;
      af[0] = (short)f2bf(f0.x); af[1] = (short)f2bf(f0.y);
      af[2] = (short)f2bf(f0.z); af[3] = (short)f2bf(f0.w);
      af[4] = (short)f2bf(f1.x); af[5] = (short)f2bf(f1.y);
      af[6] = (short)f2bf(f1.z); af[7] = (short)f2bf(f1.w);
      const unsigned short* wbk = &wb[buf][kc * 6144];
#pragma unroll
      for (int nt = 0; nt < 12; ++nt) {
        short8 bf = *(const short8*)&wbk[(nt * 16 + m) * 32 + q * 8];
        acc[nt] = __builtin_amdgcn_mfma_f32_16x16x32_bf16(af, bf, acc[nt], 0, 0, 0);
      }
    }
  }

  unsigned short* scr = &wb[0][0] + w * 1152;
#pragma unroll
  for (int nt = 0; nt < 8; ++nt)
#pragma unroll
    for (int j = 0; j < 4; ++j) {
      unsigned short val = f2bf(acc[nt][j]);
      int lrow = q * 4 + j;
      if (nt < 4) scr[lrow * 72 + nt * 16 + m] = val;
      else        sK[(w * 16 + lrow) * 72 + (nt - 4) * 16 + m] = val;
    }
#pragma unroll
  for (int nt = 8; nt < 12; ++nt) {
    ushort4 pv;
    pv.x = f2bf(acc[nt][0]); pv.y = f2bf(acc[nt][1]);
    pv.z = f2bf(acc[nt][2]); pv.w = f2bf(acc[nt][3]);
    *(ushort4*)&sVT[((nt - 8) * 16 + m) * 264 + w * 16 + q * 4] = pv;
  }

  short8 qf0 = *(const short8*)(scr + m * 72 + q * 8);
  short8 qf1 = *(const short8*)(scr + m * 72 + 32 + q * 8);
  __syncthreads();

  const float CSC = 0.18033688011112042f;
  float chk = 0.f;

#pragma unroll 1
  for (int rep = 0; rep < REPS; ++rep) {
    asm volatile("" ::: "memory");              // force re-reads each rep
    floatx4 sacc[16];
#pragma unroll
    for (int nt = 0; nt < 16; ++nt) {
      if (nt > w) continue;
      short8 kb0 = *(const short8*)(sK + (nt * 16 + m) * 72 + q * 8);
      short8 kb1 = *(const short8*)(sK + (nt * 16 + m) * 72 + 32 + q * 8);
      floatx4 t = __builtin_amdgcn_mfma_f32_16x16x32_bf16(qf0, kb0, z, 0, 0, 0);
      sacc[nt] = __builtin_amdgcn_mfma_f32_16x16x32_bf16(qf1, kb1, t, 0, 0, 0);
    }
    float inv_[4];
    int rbase = w * 16 + q * 4;
#pragma unroll
    for (int j = 0; j < 4; ++j) {
      int rg = rbase + j;
      float sum = 0.f;
#pragma unroll
      for (int nt = 0; nt < 16; ++nt) {
        if (nt > w) continue;
        int col = nt * 16 + m;
        float p = (col <= rg) ? exp2f(sacc[nt][j] * CSC) : 0.f;
        sacc[nt][j] = p;
        sum += p;
      }
      sum += __shfl_xor(sum, 1);
      sum += __shfl_xor(sum, 2);
      sum += __shfl_xor(sum, 4);
      sum += __shfl_xor(sum, 8);
      inv_[j] = 1.f / sum;
    }

    if (DO_PV) {
      floatx4 o[4];
#pragma unroll
      for (int vt = 0; vt < 4; ++vt) o[vt] = z;
#pragma unroll
      for (int c = 0; c < 4; ++c) {
        if (4 * c > w) continue;
#pragma unroll
        for (int t = 0; t < 4; ++t) {
          int nt = 4 * c + t;
#pragma unroll
          for (int j = 0; j < 4; ++j) {
            unsigned short pv = (nt <= w) ? f2bf(sacc[nt][j] * inv_[j]) : (unsigned short)0;
            scr[(q * 4 + j) * 72 + t * 16 + m] = pv;
          }
        }
        short8 pf0 = *(const short8*)(scr + m * 72 + q * 8);
        short8 pf1 = *(const short8*)(scr + m * 72 + 32 + q * 8);
#pragma unroll
        for (int vt = 0; vt < 4; ++vt) {
          short8 vb0 = *(const short8*)(sVT + (vt * 16 + m) * 264 + c * 64 + q * 8);
          short8 vb1 = *(const short8*)(sVT + (vt * 16 + m) * 264 + c * 64 + 32 + q * 8);
          o[vt] = __builtin_amdgcn_mfma_f32_16x16x32_bf16(pf0, vb0, o[vt], 0, 0, 0);
          o[vt] = __builtin_amdgcn_mfma_f32_16x16x32_bf16(pf1, vb1, o[vt], 0, 0, 0);
        }
      }
#pragma unroll
      for (int vt = 0; vt < 4; ++vt)
#pragma unroll
        for (int j = 0; j < 4; ++j) chk += o[vt][j];
    } else {
      chk += inv_[0] + inv_[1] + inv_[2] + inv_[3] + sacc[w][0];
    }
  }
  dbg[(size_t)b * 1024 + tid] = chk;
}

__global__ __launch_bounds__(1024) void probe_p3(
    const float* __restrict__ x, const unsigned short* __restrict__ wt,
    float* __restrict__ dbg) {
  probe_attn_body<5, 0>(x, wt, dbg);
}

__global__ __launch_bounds__(1024) void probe_p234(
    const float* __restrict__ x, const unsigned short* __restrict__ wt,
    float* __restrict__ dbg) {
  probe_attn_body<3, 1>(x, wt, dbg);
}

extern "C" void kernel_launch(void* const* d_in, const int* in_sizes, int n_in,
                              void* d_out, int out_size, void* d_ws, size_t ws_size,
                              hipStream_t stream) {
  const float* x  = (const float*)d_in[0];
  const float* wq = (const float*)d_in[1];
  const float* wk = (const float*)d_in[2];
  const float* wv = (const float*)d_in[3];
  float* out = (float*)d_out;

  unsigned char* ws = (unsigned char*)d_ws;
  unsigned short* wt = (unsigned short*)ws;     // Wt bf16 [192][384] = 147456 B
  float* dbg1 = (float*)(ws + (16u << 20));
  float* dbg2 = (float*)(ws + (20u << 20));
  float* dbg3 = (float*)(ws + (24u << 20));

  wt_kernel<<<288, 256, 0, stream>>>(wq, wk, wv, wt);
  fused_kernel<<<256, 1024, 0, stream>>>(x, wt, out);
  probe_p12<<<256, 1024, 0, stream>>>(x, wt, dbg1);
  probe_p3<<<256, 1024, 0, stream>>>(x, wt, dbg2);
  probe_p234<<<256, 1024, 0, stream>>>(x, wt, dbg3);
}

// Round 7
// 174.781 us; speedup vs baseline: 2.4346x; 2.4346x over previous
//
#include <hip/hip_runtime.h>

// B=256, T=256, DM=384, DK=DV=64.
// Round 7: kill the cold-x MLP stall. R6 probes showed warm P1 ~2-3us and
// warm attn ~2-3us; the champion's 59us is ~49us of COLD x fetch at 1.15TB/s
// (register float4 loads -> ~2KB/CU in flight -> latency-bound, Little's law
// matches measured BW). Fix: stage x via global_load_lds (deep async queue):
// per 32-k chunk, x-slice 32KB + W-slice 12KB double-buffered -> 44KB/CU in
// flight -> HBM BW-bound (~16us floor for phase 1).
// k0: W -> Wt bf16 [192 cols][384 k]  (coalesced-output transpose)
// k1: FUSED, one block/batch (1024 thr = 16 waves), LDS union 105KB:
//   Phase 1: 12 k-chunks; per chunk barrier -> stage(kc+1) -> compute from
//     LDS (x frags per-wave lane-bijective 1KB regions; W frags as before).
//   Phase 2: Q -> per-wave scratch, K -> sK, V^T -> sVT (regions overlay the
//     phase-1 staging area after a barrier).
//   Phase 3: S=QK^T triangular wave skip; maskless softmax (no max-subtract).
//   Phase 4: P via per-wave scratch, PV from sVT. Unchanged from champion.

typedef __attribute__((ext_vector_type(8))) short short8;
typedef __attribute__((ext_vector_type(4))) float floatx4;

__device__ inline unsigned short f2bf(float f) {
  union { float f; unsigned u; } v; v.f = f;
  unsigned r = v.u + 0x7FFFu + ((v.u >> 16) & 1u);  // RNE
  return (unsigned short)(r >> 16);
}

__device__ inline void glds16(const void* g, void* l) {
  __builtin_amdgcn_global_load_lds(
      (const __attribute__((address_space(1))) void*)g,
      (__attribute__((address_space(3))) void*)l, 16, 0, 0);
}

// ---------------- kernel 0: weight transpose/convert (output-indexed) -------
__global__ void wt_kernel(const float* __restrict__ wq, const float* __restrict__ wk,
                          const float* __restrict__ wv, unsigned short* __restrict__ wt) {
  int idx = blockIdx.x * 256 + threadIdx.x;      // enumerates OUTPUT [mat][n][k]
  if (idx >= 3 * 64 * 384) return;
  int mat = idx / (64 * 384);
  int rem = idx % (64 * 384);
  int n = rem / 384, k = rem % 384;
  const float* w = (mat == 0) ? wq : ((mat == 1) ? wk : wv);
  wt[idx] = f2bf(w[k * 64 + n]);
}

// ---------------- kernel 1: fused QKV + attention ----------------
// LDS union map (bytes, 107520 total):
//   Phase 1: [0,24576) = W dbuf 2x12288 ([192 cols][32 k] bf16)
//            [24576,90112) = x dbuf 2x32768 (per-wave 2KB, 2x 1KB lane-linear)
//   Phase 2+ (after barrier): [0,36864) sK [256][72] bf16
//            [36864,70656) sVT [64][264] bf16
//            [70656,107520) per-wave scratch 16 x [16][72] bf16 (Q then P)
__global__ __launch_bounds__(1024) void fused_kernel(
    const float* __restrict__ x, const unsigned short* __restrict__ wt,
    float* __restrict__ out) {
  __shared__ __align__(16) unsigned char U[107520];

  int tid = threadIdx.x, lane = tid & 63, w = tid >> 6;
  int m = lane & 15, q = lane >> 4;
  int b = blockIdx.x;
  const float* xb = x + (size_t)b * 256 * 384;

  // stage one 32-k chunk: x (2 issues/wave, own 16 rows) + Wt (12 issues)
  auto stage = [&](int kc, int buf) {
    unsigned char* xdst = U + 24576 + buf * 32768 + w * 2048;
    // issue g: lane l -> row w*16+(l&15), float4-idx (l>>4)*2+g of the 32-k slice
    const float* xsrc = xb + (size_t)(w * 16 + (lane & 15)) * 384 + kc * 32
                        + ((lane >> 4) * 2) * 4;
    glds16(xsrc, xdst);
    glds16(xsrc + 4, xdst + 1024);
    if (w < 12) {                                // Wt: 16 cols per issue
      int c = w * 16 + (lane >> 2), g = lane & 3;
      glds16(wt + (size_t)c * 384 + kc * 32 + g * 8, U + buf * 12288 + w * 1024);
    }
  };

  floatx4 z = {0.f, 0.f, 0.f, 0.f};
  floatx4 acc[12];
#pragma unroll
  for (int nt = 0; nt < 12; ++nt) acc[nt] = z;

  stage(0, 0);
#pragma unroll
  for (int kc = 0; kc < 12; ++kc) {
    int buf = kc & 1;
    __syncthreads();                    // buf staged (vmcnt drained); buf^1 free
    if (kc < 11) stage(kc + 1, buf ^ 1);

    // x fragments from LDS (lane-bijective 1KB regions: conflict-free b128)
    const unsigned char* xba = U + 24576 + buf * 32768 + w * 2048 + (16 * q + m) * 16;
    float4 f0 = *(const float4*)xba;
    float4 f1 = *(const float4*)(xba + 1024);
    short8 af;
    af[0] = (short)f2bf(f0.x); af[1] = (short)f2bf(f0.y);
    af[2] = (short)f2bf(f0.z); af[3] = (short)f2bf(f0.w);
    af[4] = (short)f2bf(f1.x); af[5] = (short)f2bf(f1.y);
    af[6] = (short)f2bf(f1.z); af[7] = (short)f2bf(f1.w);

    const unsigned short* wbk = (const unsigned short*)(U + buf * 12288);
#pragma unroll
    for (int nt = 0; nt < 12; ++nt) {
      // granule = (4m+q) mod 8 -> uniform 8 lanes/group: conflict-free
      short8 bf = *(const short8*)&wbk[(nt * 16 + m) * 32 + q * 8];
      acc[nt] = __builtin_amdgcn_mfma_f32_16x16x32_bf16(af, bf, acc[nt], 0, 0, 0);
    }
  }

  __syncthreads();                      // all xs/wb reads done before overlay

  // ---------- epilogue: Q -> per-wave scratch, K -> sK, V^T -> sVT ----------
  unsigned short* sK  = (unsigned short*)U;                   // [256][72]
  unsigned short* sVT = (unsigned short*)(U + 36864);         // [64][264]
  unsigned short* scr = (unsigned short*)(U + 70656) + w * 1152;  // [16][72]
#pragma unroll
  for (int nt = 0; nt < 8; ++nt) {
#pragma unroll
    for (int j = 0; j < 4; ++j) {
      unsigned short val = f2bf(acc[nt][j]);
      int lrow = q * 4 + j;                     // C-layout row within wave's 16
      if (nt < 4) scr[lrow * 72 + nt * 16 + m] = val;                  // Q
      else        sK[(w * 16 + lrow) * 72 + (nt - 4) * 16 + m] = val;  // K
    }
  }
#pragma unroll
  for (int nt = 8; nt < 12; ++nt) {             // V^T, packed 4 rows -> b64
    ushort4 pv;
    pv.x = f2bf(acc[nt][0]); pv.y = f2bf(acc[nt][1]);
    pv.z = f2bf(acc[nt][2]); pv.w = f2bf(acc[nt][3]);
    *(ushort4*)&sVT[((nt - 8) * 16 + m) * 264 + w * 16 + q * 4] = pv;
  }

  // Q fragments from own scratch (wave-local)
  short8 qf0 = *(const short8*)(scr + m * 72 + q * 8);
  short8 qf1 = *(const short8*)(scr + m * 72 + 32 + q * 8);

  __syncthreads();                              // sK, sVT visible to all waves

  // ---------- S = Q K^T (triangular: wave w needs col tiles nt <= w) ----------
  floatx4 sacc[16];
#pragma unroll
  for (int nt = 0; nt < 16; ++nt) {
    if (nt > w) continue;                       // wave-uniform skip
    short8 kb0 = *(const short8*)(sK + (nt * 16 + m) * 72 + q * 8);
    short8 kb1 = *(const short8*)(sK + (nt * 16 + m) * 72 + 32 + q * 8);
    floatx4 t = __builtin_amdgcn_mfma_f32_16x16x32_bf16(qf0, kb0, z, 0, 0, 0);
    sacc[nt] = __builtin_amdgcn_mfma_f32_16x16x32_bf16(qf1, kb1, t, 0, 0, 0);
  }

  // ---------- fused causal mask + softmax (no max-subtract) ----------
  const float CSC = 0.18033688011112042f;       // log2(e)/sqrt(64)
  float inv_[4];
  int rbase = w * 16 + q * 4;
#pragma unroll
  for (int j = 0; j < 4; ++j) {
    int rg = rbase + j;
    float sum = 0.f;
#pragma unroll
    for (int nt = 0; nt < 16; ++nt) {
      if (nt > w) continue;
      int col = nt * 16 + m;
      float p = (col <= rg) ? exp2f(sacc[nt][j] * CSC) : 0.f;
      sacc[nt][j] = p;
      sum += p;
    }
    sum += __shfl_xor(sum, 1);
    sum += __shfl_xor(sum, 2);
    sum += __shfl_xor(sum, 4);
    sum += __shfl_xor(sum, 8);
    inv_[j] = 1.f / sum;                        // diagonal term -> sum >= 1
  }

  // ---------- O = P V, chunked by 64 k-cols through per-wave scratch ----------
  floatx4 o[4];
#pragma unroll
  for (int vt = 0; vt < 4; ++vt) o[vt] = z;
#pragma unroll
  for (int c = 0; c < 4; ++c) {
    if (4 * c > w) continue;                    // chunk needed iff 64c <= 16w+15
#pragma unroll
    for (int t = 0; t < 4; ++t) {
      int nt = 4 * c + t;
#pragma unroll
      for (int j = 0; j < 4; ++j) {
        unsigned short pv = (nt <= w) ? f2bf(sacc[nt][j] * inv_[j]) : (unsigned short)0;
        scr[(q * 4 + j) * 72 + t * 16 + m] = pv;
      }
    }
    short8 pf0 = *(const short8*)(scr + m * 72 + q * 8);
    short8 pf1 = *(const short8*)(scr + m * 72 + 32 + q * 8);
#pragma unroll
    for (int vt = 0; vt < 4; ++vt) {
      short8 vb0 = *(const short8*)(sVT + (vt * 16 + m) * 264 + c * 64 + q * 8);
      short8 vb1 = *(const short8*)(sVT + (vt * 16 + m) * 264 + c * 64 + 32 + q * 8);
      o[vt] = __builtin_amdgcn_mfma_f32_16x16x32_bf16(pf0, vb0, o[vt], 0, 0, 0);
      o[vt] = __builtin_amdgcn_mfma_f32_16x16x32_bf16(pf1, vb1, o[vt], 0, 0, 0);
    }
  }

  // ---------- store O ----------
  float* op = out + ((size_t)b * 256 + w * 16) * 64;
#pragma unroll
  for (int vt = 0; vt < 4; ++vt)
#pragma unroll
    for (int j = 0; j < 4; ++j)
      op[(q * 4 + j) * 64 + vt * 16 + m] = o[vt][j];
}

extern "C" void kernel_launch(void* const* d_in, const int* in_sizes, int n_in,
                              void* d_out, int out_size, void* d_ws, size_t ws_size,
                              hipStream_t stream) {
  const float* x  = (const float*)d_in[0];
  const float* wq = (const float*)d_in[1];
  const float* wk = (const float*)d_in[2];
  const float* wv = (const float*)d_in[3];
  float* out = (float*)d_out;

  unsigned short* wt = (unsigned short*)d_ws;   // Wt bf16 [192][384] = 147456 B

  wt_kernel<<<288, 256, 0, stream>>>(wq, wk, wv, wt);
  fused_kernel<<<256, 1024, 0, stream>>>(x, wt, out);
}

// Round 8
// 173.302 us; speedup vs baseline: 2.4554x; 1.0085x over previous
//
#include <hip/hip_runtime.h>

// B=256, T=256, DM=384, DK=DV=64.
// Round 8: T3+T4 on phase 1. R7 kept __syncthreads() between chunks, which
// drains vmcnt(0): one 44KB chunk in flight, full contended-tail latency paid
// 12x -> 1.1 TB/s cold-x read (the whole 59us). Now: triple-buffered chunks,
// raw s_barrier + counted s_waitcnt vmcnt(N) (never 0 in-loop) -> 2 chunks
// (88KB/CU, ~22MB chip) continuously in flight -> BW-bound cold fetch.
// k0: W -> Wt bf16 [192 cols][384 k] (coalesced-output transpose)
// k1: FUSED, one block/batch (1024 thr = 16 waves), LDS 132KB:
//   Phase 1: 12 k-chunks; per chunk: barrier(B) -> stage(kc+2) -> counted
//     vmcnt (w<12: 6/3/0, w>=12: 4/2/0; wave-uniform branch) -> barrier(A)
//     -> compute from buf[kc%3]. x frags lane-bijective 1KB regions; W as before.
//   Phase 2: Q -> per-wave scratch, K -> sK, V^T -> sVT (overlay staging area
//     after one full __syncthreads).
//   Phase 3: S=QK^T triangular wave skip; maskless softmax (no max-subtract).
//   Phase 4: P via per-wave scratch, PV from sVT. Unchanged from champion.

typedef __attribute__((ext_vector_type(8))) short short8;
typedef __attribute__((ext_vector_type(4))) float floatx4;

__device__ inline unsigned short f2bf(float f) {
  union { float f; unsigned u; } v; v.f = f;
  unsigned r = v.u + 0x7FFFu + ((v.u >> 16) & 1u);  // RNE
  return (unsigned short)(r >> 16);
}

__device__ inline void glds16(const void* g, void* l) {
  __builtin_amdgcn_global_load_lds(
      (const __attribute__((address_space(1))) void*)g,
      (__attribute__((address_space(3))) void*)l, 16, 0, 0);
}

template <int N>
__device__ inline void vwait() {
  asm volatile("s_waitcnt vmcnt(%0)" :: "n"(N) : "memory");
}

// ---------------- kernel 0: weight transpose/convert (output-indexed) -------
__global__ void wt_kernel(const float* __restrict__ wq, const float* __restrict__ wk,
                          const float* __restrict__ wv, unsigned short* __restrict__ wt) {
  int idx = blockIdx.x * 256 + threadIdx.x;      // enumerates OUTPUT [mat][n][k]
  if (idx >= 3 * 64 * 384) return;
  int mat = idx / (64 * 384);
  int rem = idx % (64 * 384);
  int n = rem / 384, k = rem % 384;
  const float* w = (mat == 0) ? wq : ((mat == 1) ? wk : wv);
  wt[idx] = f2bf(w[k * 64 + n]);
}

// ---------------- kernel 1: fused QKV + attention ----------------
// LDS map (bytes, 135168 total):
//   Phase 1: buf i at [i*45056, i*45056+45056), i=0..2:
//            W [0,12288) = [192 cols][32 k] bf16; x [12288,45056) per-wave 2KB
//   Phase 2+ (after full __syncthreads):
//            [0,36864) sK [256][72] bf16; [36864,70656) sVT [64][264] bf16;
//            [70656,107520) per-wave scratch 16 x [16][72] bf16 (Q then P)
__global__ __launch_bounds__(1024) void fused_kernel(
    const float* __restrict__ x, const unsigned short* __restrict__ wt,
    float* __restrict__ out) {
  __shared__ __align__(16) unsigned char U[135168];

  int tid = threadIdx.x, lane = tid & 63, w = tid >> 6;
  int m = lane & 15, q = lane >> 4;
  int b = blockIdx.x;
  const float* xb = x + (size_t)b * 256 * 384;

  // stage one 32-k chunk into buf: x (2 glds16/wave) + Wt (1 glds16, w<12)
  auto stage = [&](int kc, int buf) {
    unsigned char* base = U + buf * 45056;
    const float* xsrc = xb + (size_t)(w * 16 + (lane & 15)) * 384 + kc * 32
                        + (lane >> 4) * 8;
    glds16(xsrc, base + 12288 + w * 2048);
    glds16(xsrc + 4, base + 12288 + w * 2048 + 1024);
    if (w < 12) {                                // Wt: 16 cols per issue
      int c = w * 16 + (lane >> 2), g = lane & 3;
      glds16(wt + (size_t)c * 384 + kc * 32 + g * 8, base + w * 1024);
    }
  };

  floatx4 z = {0.f, 0.f, 0.f, 0.f};
  floatx4 acc[12];
#pragma unroll
  for (int nt = 0; nt < 12; ++nt) acc[nt] = z;

  // prologue: 2 chunks in flight before first wait
  stage(0, 0);
  stage(1, 1);

#pragma unroll
  for (int kc = 0; kc < 12; ++kc) {
    int buf = kc % 3;
    // B: all waves done READING buf[(kc+2)%3] (= buf of kc-1) before overwrite
    __builtin_amdgcn_s_barrier();
    if (kc < 10) stage(kc + 2, (kc + 2) % 3);

    // counted wait: own chunk-kc loads landed; chunks kc+1,kc+2 stay in flight
    if (kc <= 9)       { if (w < 12) vwait<6>(); else vwait<4>(); }
    else if (kc == 10) { if (w < 12) vwait<3>(); else vwait<2>(); }
    else               { vwait<0>(); }
    // A: every wave passed its own vmcnt -> all of chunk kc is in LDS
    __builtin_amdgcn_s_barrier();

    // x fragments from LDS (lane-bijective 1KB regions: conflict-free b128)
    const unsigned char* xba = U + buf * 45056 + 12288 + w * 2048 + (16 * q + m) * 16;
    float4 f0 = *(const float4*)xba;
    float4 f1 = *(const float4*)(xba + 1024);
    short8 af;
    af[0] = (short)f2bf(f0.x); af[1] = (short)f2bf(f0.y);
    af[2] = (short)f2bf(f0.z); af[3] = (short)f2bf(f0.w);
    af[4] = (short)f2bf(f1.x); af[5] = (short)f2bf(f1.y);
    af[6] = (short)f2bf(f1.z); af[7] = (short)f2bf(f1.w);

    const unsigned short* wbk = (const unsigned short*)(U + buf * 45056);
#pragma unroll
    for (int nt = 0; nt < 12; ++nt) {
      // granule = (4m+q) mod 8 -> uniform 8 lanes/group: conflict-free
      short8 bf = *(const short8*)&wbk[(nt * 16 + m) * 32 + q * 8];
      acc[nt] = __builtin_amdgcn_mfma_f32_16x16x32_bf16(af, bf, acc[nt], 0, 0, 0);
    }
  }

  __syncthreads();                      // full drain once; staging area now dead

  // ---------- epilogue: Q -> per-wave scratch, K -> sK, V^T -> sVT ----------
  unsigned short* sK  = (unsigned short*)U;                   // [256][72]
  unsigned short* sVT = (unsigned short*)(U + 36864);         // [64][264]
  unsigned short* scr = (unsigned short*)(U + 70656) + w * 1152;  // [16][72]
#pragma unroll
  for (int nt = 0; nt < 8; ++nt) {
#pragma unroll
    for (int j = 0; j < 4; ++j) {
      unsigned short val = f2bf(acc[nt][j]);
      int lrow = q * 4 + j;                     // C-layout row within wave's 16
      if (nt < 4) scr[lrow * 72 + nt * 16 + m] = val;                  // Q
      else        sK[(w * 16 + lrow) * 72 + (nt - 4) * 16 + m] = val;  // K
    }
  }
#pragma unroll
  for (int nt = 8; nt < 12; ++nt) {             // V^T, packed 4 rows -> b64
    ushort4 pv;
    pv.x = f2bf(acc[nt][0]); pv.y = f2bf(acc[nt][1]);
    pv.z = f2bf(acc[nt][2]); pv.w = f2bf(acc[nt][3]);
    *(ushort4*)&sVT[((nt - 8) * 16 + m) * 264 + w * 16 + q * 4] = pv;
  }

  // Q fragments from own scratch (wave-local)
  short8 qf0 = *(const short8*)(scr + m * 72 + q * 8);
  short8 qf1 = *(const short8*)(scr + m * 72 + 32 + q * 8);

  __syncthreads();                              // sK, sVT visible to all waves

  // ---------- S = Q K^T (triangular: wave w needs col tiles nt <= w) ----------
  floatx4 sacc[16];
#pragma unroll
  for (int nt = 0; nt < 16; ++nt) {
    if (nt > w) continue;                       // wave-uniform skip
    short8 kb0 = *(const short8*)(sK + (nt * 16 + m) * 72 + q * 8);
    short8 kb1 = *(const short8*)(sK + (nt * 16 + m) * 72 + 32 + q * 8);
    floatx4 t = __builtin_amdgcn_mfma_f32_16x16x32_bf16(qf0, kb0, z, 0, 0, 0);
    sacc[nt] = __builtin_amdgcn_mfma_f32_16x16x32_bf16(qf1, kb1, t, 0, 0, 0);
  }

  // ---------- fused causal mask + softmax (no max-subtract) ----------
  const float CSC = 0.18033688011112042f;       // log2(e)/sqrt(64)
  float inv_[4];
  int rbase = w * 16 + q * 4;
#pragma unroll
  for (int j = 0; j < 4; ++j) {
    int rg = rbase + j;
    float sum = 0.f;
#pragma unroll
    for (int nt = 0; nt < 16; ++nt) {
      if (nt > w) continue;
      int col = nt * 16 + m;
      float p = (col <= rg) ? exp2f(sacc[nt][j] * CSC) : 0.f;
      sacc[nt][j] = p;
      sum += p;
    }
    sum += __shfl_xor(sum, 1);
    sum += __shfl_xor(sum, 2);
    sum += __shfl_xor(sum, 4);
    sum += __shfl_xor(sum, 8);
    inv_[j] = 1.f / sum;                        // diagonal term -> sum >= 1
  }

  // ---------- O = P V, chunked by 64 k-cols through per-wave scratch ----------
  floatx4 o[4];
#pragma unroll
  for (int vt = 0; vt < 4; ++vt) o[vt] = z;
#pragma unroll
  for (int c = 0; c < 4; ++c) {
    if (4 * c > w) continue;                    // chunk needed iff 64c <= 16w+15
#pragma unroll
    for (int t = 0; t < 4; ++t) {
      int nt = 4 * c + t;
#pragma unroll
      for (int j = 0; j < 4; ++j) {
        unsigned short pv = (nt <= w) ? f2bf(sacc[nt][j] * inv_[j]) : (unsigned short)0;
        scr[(q * 4 + j) * 72 + t * 16 + m] = pv;
      }
    }
    short8 pf0 = *(const short8*)(scr + m * 72 + q * 8);
    short8 pf1 = *(const short8*)(scr + m * 72 + 32 + q * 8);
#pragma unroll
    for (int vt = 0; vt < 4; ++vt) {
      short8 vb0 = *(const short8*)(sVT + (vt * 16 + m) * 264 + c * 64 + q * 8);
      short8 vb1 = *(const short8*)(sVT + (vt * 16 + m) * 264 + c * 64 + 32 + q * 8);
      o[vt] = __builtin_amdgcn_mfma_f32_16x16x32_bf16(pf0, vb0, o[vt], 0, 0, 0);
      o[vt] = __builtin_amdgcn_mfma_f32_16x16x32_bf16(pf1, vb1, o[vt], 0, 0, 0);
    }
  }

  // ---------- store O ----------
  float* op = out + ((size_t)b * 256 + w * 16) * 64;
#pragma unroll
  for (int vt = 0; vt < 4; ++vt)
#pragma unroll
    for (int j = 0; j < 4; ++j)
      op[(q * 4 + j) * 64 + vt * 16 + m] = o[vt][j];
}

extern "C" void kernel_launch(void* const* d_in, const int* in_sizes, int n_in,
                              void* d_out, int out_size, void* d_ws, size_t ws_size,
                              hipStream_t stream) {
  const float* x  = (const float*)d_in[0];
  const float* wq = (const float*)d_in[1];
  const float* wk = (const float*)d_in[2];
  const float* wv = (const float*)d_in[3];
  float* out = (float*)d_out;

  unsigned short* wt = (unsigned short*)d_ws;   // Wt bf16 [192][384] = 147456 B

  wt_kernel<<<288, 256, 0, stream>>>(wq, wk, wv, wt);
  fused_kernel<<<256, 1024, 0, stream>>>(x, wt, out);
}